// Round 7
// baseline (611.277 us; speedup 1.0000x reference)
//
#include <hip/hip_runtime.h>

#define NUM_CLASSES 1000
#define FEAT_DIM    256
#define MOMENTUM    0.9f
#define NCHUNK      32          // row chunks
#define NSLICE      8           // dim slices (8 x 32 = 256)
#define SLICE_DIM   32
#define ACCT        1024        // accumulate block threads
#define ACC_PITCH   33          // padded class pitch -> bank (c+d)%32

// ---------------------------------------------------------------------------
// Kernel 1: direct accumulation. Block (slice, chunk) streams a contiguous
// 8192-row chunk, reads its 32-dim slice of each row (float4 per lane,
// 8 rows x 8 dim-groups per wave), and accumulates into a padded LDS table
// acc[1000][33] with ds_add_f32 atomics. Slice 0 also histograms labels.
// Partial sums go to ws coalesced; every psum/cnt_r slot is fully written.
// ---------------------------------------------------------------------------
__global__ void __launch_bounds__(ACCT, 1) accum_kernel(
    const float* __restrict__ feat, const int* __restrict__ labels,
    int lstride, int n, int rpc,
    float* __restrict__ psum, int* __restrict__ cnt_r) {
    extern __shared__ float smem[];
    float* acc = smem;                                    // [1000*33]
    int*   cnt = (int*)(smem + NUM_CLASSES * ACC_PITCH);  // [1000]

    const int slice = blockIdx.x;   // 0..NSLICE-1
    const int chunk = blockIdx.y;   // 0..NCHUNK-1
    const int t     = threadIdx.x;

    for (int i = t; i < NUM_CLASSES * ACC_PITCH; i += ACCT) acc[i] = 0.f;
    for (int i = t; i < NUM_CLASSES; i += ACCT) cnt[i] = 0;
    __syncthreads();

    const int row0 = chunk * rpc;
    const int row1 = min(n, row0 + rpc);
    const int dg   = t & 7;         // dim-group within slice (4 dims each)
    const bool do_cnt = (slice == 0) && (dg == 0);
    const float4* feat4 = reinterpret_cast<const float4*>(feat);

#pragma unroll 2
    for (int row = row0 + (t >> 3); row < row1; row += ACCT / 8) {
        int lab = labels[(size_t)row * lstride];
        float4 f = feat4[(size_t)row * (FEAT_DIM / 4) + slice * (SLICE_DIM / 4) + dg];
        int b = lab * ACC_PITCH + dg * 4;
        atomicAdd(&acc[b + 0], f.x);
        atomicAdd(&acc[b + 1], f.y);
        atomicAdd(&acc[b + 2], f.z);
        atomicAdd(&acc[b + 3], f.w);
        if (do_cnt) atomicAdd(&cnt[lab], 1);
    }
    __syncthreads();

    float* pout = psum + (size_t)(chunk * NSLICE + slice) * (NUM_CLASSES * SLICE_DIM);
    for (int i = t; i < NUM_CLASSES * SLICE_DIM; i += ACCT) {
        int c = i >> 5, d = i & 31;
        pout[i] = acc[c * ACC_PITCH + d];
    }
    if (slice == 0)
        for (int i = t; i < NUM_CLASSES; i += ACCT)
            cnt_r[chunk * NUM_CLASSES + i] = cnt[i];
}

// ---------------------------------------------------------------------------
// Kernel 2: finalize. Block = class, thread = dim. Sum the 32 chunk partials
// (coalesced 128 B per 32-thread group), compute count, EMA + present mask.
// ---------------------------------------------------------------------------
__global__ void __launch_bounds__(FEAT_DIM) finalize_kernel(
    const float* __restrict__ psum, const int* __restrict__ cnt_r,
    const float* __restrict__ proto, float* __restrict__ out) {
    const int c = blockIdx.x;
    const int d = threadIdx.x;          // 0..255
    const int slice = d >> 5, dd = d & 31;

    int cnt = 0;
#pragma unroll 8
    for (int k = 0; k < NCHUNK; ++k) cnt += cnt_r[k * NUM_CLASSES + c];

    float s = 0.f;
#pragma unroll 4
    for (int k = 0; k < NCHUNK; ++k)
        s += psum[((size_t)(k * NSLICE + slice) * NUM_CLASSES + c) * SLICE_DIM + dd];

    float p = proto[(size_t)c * FEAT_DIM + d];
    float r = p;
    if (cnt > 0) r = MOMENTUM * p + (1.0f - MOMENTUM) * (s / (float)cnt);
    out[(size_t)c * FEAT_DIM + d] = r;
}

// ---------------------------------------------------------------------------
extern "C" void kernel_launch(void* const* d_in, const int* in_sizes, int n_in,
                              void* d_out, int out_size, void* d_ws, size_t ws_size,
                              hipStream_t stream) {
    const float* feat   = (const float*)d_in[0];
    const int*   labels = (const int*)d_in[1];
    const float* proto  = (const float*)d_in[2];
    float*       out    = (float*)d_out;

    const int n = in_sizes[0] / FEAT_DIM;   // 262144
    // labels may be int64 surfaced as 2N int32 words (read LE low word,
    // stride 2) or plain int32 (stride 1).
    const int lstride = (in_sizes[1] >= 2 * n) ? 2 : 1;
    const int rpc = (n + NCHUNK - 1) / NCHUNK;   // rows per chunk (8192)

    // Workspace layout (poisoned each launch; all slots fully overwritten):
    char* ws = (char*)d_ws;
    int*   cnt_r = (int*)(ws + 0);              // NCHUNK*1000 ints (128 KB)
    float* psum  = (float*)(ws + (256 << 10));  // NCHUNK*NSLICE*1000*32 f32 (32.768 MB)

    const size_t shbytes = (size_t)NUM_CLASSES * ACC_PITCH * sizeof(float)
                         + (size_t)NUM_CLASSES * sizeof(int);   // 136,000 B

    dim3 grid(NSLICE, NCHUNK);
    accum_kernel<<<grid, ACCT, shbytes, stream>>>(
        feat, labels, lstride, n, rpc, psum, cnt_r);
    finalize_kernel<<<NUM_CLASSES, FEAT_DIM, 0, stream>>>(
        psum, cnt_r, proto, out);
}